// Round 7
// baseline (97.533 us; speedup 1.0000x reference)
//
#include <hip/hip_runtime.h>
#include <stdint.h>

#define N 4096
#define D 1024            // elements per row; i8 => 1024 bytes per row
#define MARGIN 0.1f
#define BM 256
#define BN 256
#define BKB 128           // K-slab per tile in bytes (=128 elements)
#define QS 500.0f         // i8 quant scale: |elem| of unit rows < 0.2 -> |q| < 100
#define INVQS2 (1.0f / (QS * QS))

typedef __attribute__((ext_vector_type(4))) int i32x4;

// Kernel 1: one wave per row (4 rows/block): fp32 norms + diagonal dot,
// butterfly shfl_xor reduce, write normalized rows quantized to int8
// (q = round(QS * w / ||w||), QS=500). d_i kept fp32-exact. Unchanged
// from R13 (verified absmax=0).
__global__ __launch_bounds__(256) void prep_kernel(
    const float* __restrict__ W, const float* __restrict__ O,
    uint8_t* __restrict__ Wn, uint8_t* __restrict__ On,
    float* __restrict__ dvec, float* __restrict__ out) {
  const int wv = threadIdx.x >> 6, ln = threadIdx.x & 63;
  const int row = blockIdx.x * 4 + wv;
  if (blockIdx.x == 0 && threadIdx.x == 0) *out = 0.0f;
  const float4* Wr = (const float4*)(W + (size_t)row * D);
  const float4* Or = (const float4*)(O + (size_t)row * D);
  float4 w[4], o[4];
  float sw = 0.f, so = 0.f, sd = 0.f;
  #pragma unroll
  for (int c = 0; c < 4; ++c) {
    w[c] = Wr[ln + c * 64];
    o[c] = Or[ln + c * 64];
    sw += w[c].x * w[c].x + w[c].y * w[c].y + w[c].z * w[c].z + w[c].w * w[c].w;
    so += o[c].x * o[c].x + o[c].y * o[c].y + o[c].z * o[c].z + o[c].w * o[c].w;
    sd += w[c].x * o[c].x + w[c].y * o[c].y + w[c].z * o[c].z + w[c].w * o[c].w;
  }
  #pragma unroll
  for (int off = 1; off < 64; off <<= 1) {
    sw += __shfl_xor(sw, off, 64);
    so += __shfl_xor(so, off, 64);
    sd += __shfl_xor(sd, off, 64);
  }
  const float inw = 1.0f / sqrtf(sw) * QS;
  const float ino = 1.0f / sqrtf(so) * QS;
  if (ln == 0) dvec[row] = sd * inw * ino * INVQS2;
  int* Wo = (int*)(Wn + (size_t)row * D);
  int* Oo = (int*)(On + (size_t)row * D);
  #pragma unroll
  for (int c = 0; c < 4; ++c) {
    int q0 = __float2int_rn(fminf(fmaxf(w[c].x * inw, -127.f), 127.f));
    int q1 = __float2int_rn(fminf(fmaxf(w[c].y * inw, -127.f), 127.f));
    int q2 = __float2int_rn(fminf(fmaxf(w[c].z * inw, -127.f), 127.f));
    int q3 = __float2int_rn(fminf(fmaxf(w[c].w * inw, -127.f), 127.f));
    Wo[ln + c * 64] = (q0 & 255) | ((q1 & 255) << 8) | ((q2 & 255) << 16) |
                      ((q3 & 255) << 24);
    q0 = __float2int_rn(fminf(fmaxf(o[c].x * ino, -127.f), 127.f));
    q1 = __float2int_rn(fminf(fmaxf(o[c].y * ino, -127.f), 127.f));
    q2 = __float2int_rn(fminf(fmaxf(o[c].z * ino, -127.f), 127.f));
    q3 = __float2int_rn(fminf(fmaxf(o[c].w * ino, -127.f), 127.f));
    Oo[ln + c * 64] = (q0 & 255) | ((q1 & 255) << 8) | ((q2 & 255) << 16) |
                      ((q3 & 255) << 24);
  }
}

// Kernel 2: 256x256-tile INT8 GEMM + fused loss, counted-vmcnt pipeline.
// R16 = R15 + two structure-preserving catalog levers:
//  (a) T5 s_setprio(1) around each MFMA cluster — R15's counted-vmcnt
//      schedule creates the wave role-diversity that is T5's
//      prerequisite (m218b: +21-25% with it, 0% without).
//  (b) 2D-chunked XCD swizzle: grid 256 = 1 block/CU all-resident;
//      default round-robin gives each XCD a 2x16 tile strip (per-kt L2
//      fill 18 slabs, ~36 MB total). Remap so each XCD owns an 8x4
//      rectangle: per-kt fill 12 slabs, ~24 MB, 3 MB/XCD working set
//      fits the 4 MB L2. Bijective for 256 blocks (256%8==0).
// R15 core (verified absmax=0): 8 waves, 128x64 wave tiles, i8 fragment
// = one native i32x4 = one swizzled 16B granule per lane, double-buffered
// BKB=128, raw s_barrier + s_waitcnt vmcnt(8) (never drain in-loop).
__global__ __launch_bounds__(512) void gemm_loss_kernel(
    const uint8_t* __restrict__ Wn, const uint8_t* __restrict__ On,
    const float* __restrict__ dvec, float* __restrict__ out) {
  __shared__ __align__(16) uint8_t ldsA0[BM * BKB];  // 32 KB
  __shared__ __align__(16) uint8_t ldsB0[BN * BKB];  // 32 KB
  __shared__ __align__(16) uint8_t ldsA1[BM * BKB];  // 32 KB
  __shared__ __align__(16) uint8_t ldsB1[BN * BKB];  // 32 KB
  // XCD-chunked remap: HW sends original bid round-robin (xcd = bid%8);
  // give XCD x the 32 tiles of an 8-wide x 4-tall rectangle.
  const int bid = blockIdx.y * 16 + blockIdx.x;
  const int chunk = bid >> 5, j = bid & 31;
  const int by = (chunk >> 1) * 4 + (j >> 3);
  const int bx = (chunk & 1) * 8 + (j & 7);
  const int t = threadIdx.x;
  const int wv = t >> 6, ln = t & 63;
  const int wm = wv >> 2, wn = wv & 3;   // 2x4 wave grid, 128x64 per wave
  const int lrow = ln & 15;
  const int quad = ln >> 4;
  const int l7 = lrow & 7;               // == rr&7 == cc&7 for fragment rows

  i32x4 acc[8][4] = {};                  // exact int32 accumulation

  const uint8_t* Ag = Wn + (size_t)(by * BM) * D;
  const uint8_t* Bg = On + (size_t)(bx * BN) * D;

  // stage 256 rows x 128 B per tile = 2048 granules(16B); 512 thr x 4 rounds
#define STAGE(dstA, dstB, ktv) do {                                          \
    _Pragma("unroll")                                                        \
    for (int c_ = 0; c_ < 4; ++c_) {                                         \
      const int g_ = c_ * 512 + t;       /* granule index (fixed LDS slot)*/ \
      const int r_ = g_ >> 3;            /* tile row (8 granules per row) */ \
      const int gi_ = g_ & 7;            /* granule slot within row */       \
      const int col_ = (gi_ ^ (r_ & 7)) << 4;  /* swizzled global byte col */\
      __builtin_amdgcn_global_load_lds(                                      \
          (const __attribute__((address_space(1))) void*)(                   \
              Ag + (size_t)r_ * D + (ktv) * BKB + col_),                     \
          (__attribute__((address_space(3))) void*)((dstA) + g_ * 16),       \
          16, 0, 0);                                                         \
      __builtin_amdgcn_global_load_lds(                                      \
          (const __attribute__((address_space(1))) void*)(                   \
              Bg + (size_t)r_ * D + (ktv) * BKB + col_),                     \
          (__attribute__((address_space(3))) void*)((dstB) + g_ * 16),       \
          16, 0, 0);                                                         \
    }                                                                        \
  } while (0)

#define COMPUTE(srcA, srcB) do {                                             \
    _Pragma("unroll")                                                        \
    for (int kk = 0; kk < 2; ++kk) {     /* two K=64 steps per 128B slab */  \
      /* lane's 16 k-bytes = slab granule G = kk*4+quad, at slot G^l7 */     \
      const int s0 = ((kk * 4 + quad) ^ l7) << 4;                            \
      i32x4 aF[8], bF[4];                                                    \
      _Pragma("unroll")                                                      \
      for (int mi = 0; mi < 8; ++mi) {                                       \
        const int rr = wm * 128 + mi * 16 + lrow;                            \
        aF[mi] = *(const i32x4*)((srcA) + rr * BKB + s0);                    \
      }                                                                      \
      _Pragma("unroll")                                                      \
      for (int ni = 0; ni < 4; ++ni) {                                       \
        const int cc = wn * 64 + ni * 16 + lrow;                             \
        bF[ni] = *(const i32x4*)((srcB) + cc * BKB + s0);                    \
      }                                                                      \
      __builtin_amdgcn_s_setprio(1);     /* T5: favor MFMA-issuing wave */   \
      _Pragma("unroll")                                                      \
      for (int mi = 0; mi < 8; ++mi)                                         \
        _Pragma("unroll")                                                    \
        for (int ni = 0; ni < 4; ++ni)                                       \
          acc[mi][ni] = __builtin_amdgcn_mfma_i32_16x16x64_i8(               \
              aF[mi], bF[ni], acc[mi][ni], 0, 0, 0);                         \
      __builtin_amdgcn_s_setprio(0);                                         \
    }                                                                        \
  } while (0)

#define WAITV(n_lit) do {                                                    \
    asm volatile("s_waitcnt vmcnt(" #n_lit ")" ::: "memory");                \
    __builtin_amdgcn_sched_barrier(0);                                       \
  } while (0)
#define BARRIER() do {                                                       \
    __builtin_amdgcn_sched_barrier(0);                                       \
    __builtin_amdgcn_s_barrier();                                            \
    __builtin_amdgcn_sched_barrier(0);                                       \
  } while (0)

  STAGE(ldsA0, ldsB0, 0);                                   // 8 in flight
  STAGE(ldsA1, ldsB1, 1); WAITV(8); BARRIER();              // slab0 landed
  COMPUTE(ldsA0, ldsB0); BARRIER();
  STAGE(ldsA0, ldsB0, 2); WAITV(8); BARRIER();
  COMPUTE(ldsA1, ldsB1); BARRIER();
  STAGE(ldsA1, ldsB1, 3); WAITV(8); BARRIER();
  COMPUTE(ldsA0, ldsB0); BARRIER();
  STAGE(ldsA0, ldsB0, 4); WAITV(8); BARRIER();
  COMPUTE(ldsA1, ldsB1); BARRIER();
  STAGE(ldsA1, ldsB1, 5); WAITV(8); BARRIER();
  COMPUTE(ldsA0, ldsB0); BARRIER();
  STAGE(ldsA0, ldsB0, 6); WAITV(8); BARRIER();
  COMPUTE(ldsA1, ldsB1); BARRIER();
  STAGE(ldsA1, ldsB1, 7); WAITV(8); BARRIER();
  COMPUTE(ldsA0, ldsB0); BARRIER();
  WAITV(0); BARRIER();                                      // drain slab 7
  COMPUTE(ldsA1, ldsB1);

  // Epilogue: C/D layout col=lane&15, row=quad*4+reg (shape-determined,
  // dtype-independent, verified m89/m121 + in-session absmax=0)
  float lsum = 0.0f;
  #pragma unroll
  for (int mi = 0; mi < 8; ++mi) {
    const int gibase = by * BM + wm * 128 + mi * 16 + quad * 4;
    #pragma unroll
    for (int r = 0; r < 4; ++r) {
      const int gi = gibase + r;
      const float di = dvec[gi];  // fp32 diagonal (accurate)
      #pragma unroll
      for (int ni = 0; ni < 4; ++ni) {
        const int gj = bx * BN + wn * 64 + ni * 16 + lrow;
        const float s = (float)acc[mi][ni][r] * INVQS2;
        lsum += (gi == gj) ? (1.0f - s) : fmaxf(MARGIN - s + di, 0.0f);
      }
    }
  }
  #pragma unroll
  for (int off = 32; off; off >>= 1) lsum += __shfl_down(lsum, off, 64);
  __shared__ float bsum[8];
  if (ln == 0) bsum[wv] = lsum;
  __syncthreads();
  if (t == 0) {
    float tot = 0.f;
    #pragma unroll
    for (int i = 0; i < 8; ++i) tot += bsum[i];
    atomicAdd(out, tot * (1.0f / ((float)N * (float)N)));
  }
}

extern "C" void kernel_launch(void* const* d_in, const int* in_sizes, int n_in,
                              void* d_out, int out_size, void* d_ws, size_t ws_size,
                              hipStream_t stream) {
  const float* W = (const float*)d_in[0];  // wsi_embeddings (N,1,D)
  const float* O = (const float*)d_in[1];  // omic_embeddings (N,1,D)
  uint8_t* Wn = (uint8_t*)d_ws;                     // 4 MB i8
  uint8_t* On = Wn + (size_t)N * D;                 // 4 MB i8
  float* dvec = (float*)(On + (size_t)N * D);       // 16 KB
  float* out = (float*)d_out;

  prep_kernel<<<N / 4, 256, 0, stream>>>(W, O, Wn, On, dvec, out);
  dim3 grid(N / BN, N / BM);  // 16 x 16 = 256 blocks = 1 per CU
  gemm_loss_kernel<<<grid, 512, 0, stream>>>(Wn, On, dvec, out);
}

// Round 8
// 95.501 us; speedup vs baseline: 1.0213x; 1.0213x over previous
//
#include <hip/hip_runtime.h>
#include <stdint.h>

#define N 4096
#define D 1024            // elements per row; i8 => 1024 bytes per row
#define MARGIN 0.1f
#define BM 256
#define BN 256
#define BKB 128           // K-slab per tile in bytes (=128 elements)
#define QS 500.0f         // i8 quant scale: |elem| of unit rows < 0.2 -> |q| < 100
#define INVQS2 (1.0f / (QS * QS))

typedef __attribute__((ext_vector_type(4))) int i32x4;

// Kernel 1: one wave per row (4 rows/block): fp32 norms + diagonal dot,
// butterfly shfl_xor reduce, write normalized rows quantized to int8
// (q = round(QS * w / ||w||), QS=500). d_i kept fp32-exact. Unchanged
// from R13 (verified absmax=0).
__global__ __launch_bounds__(256) void prep_kernel(
    const float* __restrict__ W, const float* __restrict__ O,
    uint8_t* __restrict__ Wn, uint8_t* __restrict__ On,
    float* __restrict__ dvec, float* __restrict__ out) {
  const int wv = threadIdx.x >> 6, ln = threadIdx.x & 63;
  const int row = blockIdx.x * 4 + wv;
  if (blockIdx.x == 0 && threadIdx.x == 0) *out = 0.0f;
  const float4* Wr = (const float4*)(W + (size_t)row * D);
  const float4* Or = (const float4*)(O + (size_t)row * D);
  float4 w[4], o[4];
  float sw = 0.f, so = 0.f, sd = 0.f;
  #pragma unroll
  for (int c = 0; c < 4; ++c) {
    w[c] = Wr[ln + c * 64];
    o[c] = Or[ln + c * 64];
    sw += w[c].x * w[c].x + w[c].y * w[c].y + w[c].z * w[c].z + w[c].w * w[c].w;
    so += o[c].x * o[c].x + o[c].y * o[c].y + o[c].z * o[c].z + o[c].w * o[c].w;
    sd += w[c].x * o[c].x + w[c].y * o[c].y + w[c].z * o[c].z + w[c].w * o[c].w;
  }
  #pragma unroll
  for (int off = 1; off < 64; off <<= 1) {
    sw += __shfl_xor(sw, off, 64);
    so += __shfl_xor(so, off, 64);
    sd += __shfl_xor(sd, off, 64);
  }
  const float inw = 1.0f / sqrtf(sw) * QS;
  const float ino = 1.0f / sqrtf(so) * QS;
  if (ln == 0) dvec[row] = sd * inw * ino * INVQS2;
  int* Wo = (int*)(Wn + (size_t)row * D);
  int* Oo = (int*)(On + (size_t)row * D);
  #pragma unroll
  for (int c = 0; c < 4; ++c) {
    int q0 = __float2int_rn(fminf(fmaxf(w[c].x * inw, -127.f), 127.f));
    int q1 = __float2int_rn(fminf(fmaxf(w[c].y * inw, -127.f), 127.f));
    int q2 = __float2int_rn(fminf(fmaxf(w[c].z * inw, -127.f), 127.f));
    int q3 = __float2int_rn(fminf(fmaxf(w[c].w * inw, -127.f), 127.f));
    Wo[ln + c * 64] = (q0 & 255) | ((q1 & 255) << 8) | ((q2 & 255) << 16) |
                      ((q3 & 255) << 24);
    q0 = __float2int_rn(fminf(fmaxf(o[c].x * ino, -127.f), 127.f));
    q1 = __float2int_rn(fminf(fmaxf(o[c].y * ino, -127.f), 127.f));
    q2 = __float2int_rn(fminf(fmaxf(o[c].z * ino, -127.f), 127.f));
    q3 = __float2int_rn(fminf(fmaxf(o[c].w * ino, -127.f), 127.f));
    Oo[ln + c * 64] = (q0 & 255) | ((q1 & 255) << 8) | ((q2 & 255) << 16) |
                      ((q3 & 255) << 24);
  }
}

// Kernel 2: 256x256-tile INT8 GEMM + fused loss, counted-vmcnt pipeline.
// R17 = R15 core (setprio + miskeyed XCD swizzle of R16 both reverted:
// swizzle keyed bid>>5 but HW XCDs key bid%8 -> footprint no-op; setprio
// negative on non-fine-phased GEMM, matching m190) + ONE lever:
// REGISTER-LEVEL FRAGMENT DOUBLE-BUFFER. R15's COMPUTE was
// {12 ds_read -> 32 MFMA} x2: all 8 waves burst reads (DS saturated,
// MFMA idle) then burst MFMAs (DS idle); slab span ~DS+MFMA instead of
// max(DS, MFMA). Fix: issue ALL 24 frag reads (both kk halves) up
// front, then the 64 MFMAs — compiler's counted lgkmcnt starts kk0
// MFMAs when their frags land while DS serves kk1 reads underneath.
// Register budget (R11/R12 hazard, checked): 24 live i32x4 frags (96)
// + acc 128 + addressing ~= 240 < 256; plain-array idiom only.
// R15 core (verified absmax=0): 8 waves, 128x64 wave tiles, i8 fragment
// = one native i32x4 = one swizzled 16B granule per lane, double-buffered
// BKB=128, raw s_barrier + s_waitcnt vmcnt(8) (never drain in-loop).
__global__ __launch_bounds__(512) void gemm_loss_kernel(
    const uint8_t* __restrict__ Wn, const uint8_t* __restrict__ On,
    const float* __restrict__ dvec, float* __restrict__ out) {
  __shared__ __align__(16) uint8_t ldsA0[BM * BKB];  // 32 KB
  __shared__ __align__(16) uint8_t ldsB0[BN * BKB];  // 32 KB
  __shared__ __align__(16) uint8_t ldsA1[BM * BKB];  // 32 KB
  __shared__ __align__(16) uint8_t ldsB1[BN * BKB];  // 32 KB
  const int bx = blockIdx.x, by = blockIdx.y;
  const int t = threadIdx.x;
  const int wv = t >> 6, ln = t & 63;
  const int wm = wv >> 2, wn = wv & 3;   // 2x4 wave grid, 128x64 per wave
  const int lrow = ln & 15;
  const int quad = ln >> 4;
  const int l7 = lrow & 7;               // == rr&7 == cc&7 for fragment rows

  i32x4 acc[8][4] = {};                  // exact int32 accumulation

  const uint8_t* Ag = Wn + (size_t)(by * BM) * D;
  const uint8_t* Bg = On + (size_t)(bx * BN) * D;

  // stage 256 rows x 128 B per tile = 2048 granules(16B); 512 thr x 4 rounds
#define STAGE(dstA, dstB, ktv) do {                                          \
    _Pragma("unroll")                                                        \
    for (int c_ = 0; c_ < 4; ++c_) {                                         \
      const int g_ = c_ * 512 + t;       /* granule index (fixed LDS slot)*/ \
      const int r_ = g_ >> 3;            /* tile row (8 granules per row) */ \
      const int gi_ = g_ & 7;            /* granule slot within row */       \
      const int col_ = (gi_ ^ (r_ & 7)) << 4;  /* swizzled global byte col */\
      __builtin_amdgcn_global_load_lds(                                      \
          (const __attribute__((address_space(1))) void*)(                   \
              Ag + (size_t)r_ * D + (ktv) * BKB + col_),                     \
          (__attribute__((address_space(3))) void*)((dstA) + g_ * 16),       \
          16, 0, 0);                                                         \
      __builtin_amdgcn_global_load_lds(                                      \
          (const __attribute__((address_space(1))) void*)(                   \
              Bg + (size_t)r_ * D + (ktv) * BKB + col_),                     \
          (__attribute__((address_space(3))) void*)((dstB) + g_ * 16),       \
          16, 0, 0);                                                         \
    }                                                                        \
  } while (0)

  // Register-dbuf COMPUTE: all 24 frag reads issued first (kk0 then kk1),
  // then 64 MFMAs. lgkmcnt pipelining overlaps kk1 reads under kk0 MFMAs.
#define COMPUTE(srcA, srcB) do {                                             \
    const int s0a = ((0 * 4 + quad) ^ l7) << 4;  /* kk0 granule slot */      \
    const int s0b = ((1 * 4 + quad) ^ l7) << 4;  /* kk1 granule slot */      \
    i32x4 aF0[8], bF0[4], aF1[8], bF1[4];                                    \
    _Pragma("unroll")                                                        \
    for (int mi = 0; mi < 8; ++mi) {                                         \
      const int rr = wm * 128 + mi * 16 + lrow;                              \
      aF0[mi] = *(const i32x4*)((srcA) + rr * BKB + s0a);                    \
    }                                                                        \
    _Pragma("unroll")                                                        \
    for (int ni = 0; ni < 4; ++ni) {                                         \
      const int cc = wn * 64 + ni * 16 + lrow;                               \
      bF0[ni] = *(const i32x4*)((srcB) + cc * BKB + s0a);                    \
    }                                                                        \
    _Pragma("unroll")                                                        \
    for (int mi = 0; mi < 8; ++mi) {                                         \
      const int rr = wm * 128 + mi * 16 + lrow;                              \
      aF1[mi] = *(const i32x4*)((srcA) + rr * BKB + s0b);                    \
    }                                                                        \
    _Pragma("unroll")                                                        \
    for (int ni = 0; ni < 4; ++ni) {                                         \
      const int cc = wn * 64 + ni * 16 + lrow;                               \
      bF1[ni] = *(const i32x4*)((srcB) + cc * BKB + s0b);                    \
    }                                                                        \
    _Pragma("unroll")                                                        \
    for (int mi = 0; mi < 8; ++mi)                                           \
      _Pragma("unroll")                                                      \
      for (int ni = 0; ni < 4; ++ni)                                         \
        acc[mi][ni] = __builtin_amdgcn_mfma_i32_16x16x64_i8(                 \
            aF0[mi], bF0[ni], acc[mi][ni], 0, 0, 0);                         \
    _Pragma("unroll")                                                        \
    for (int mi = 0; mi < 8; ++mi)                                           \
      _Pragma("unroll")                                                      \
      for (int ni = 0; ni < 4; ++ni)                                         \
        acc[mi][ni] = __builtin_amdgcn_mfma_i32_16x16x64_i8(                 \
            aF1[mi], bF1[ni], acc[mi][ni], 0, 0, 0);                         \
  } while (0)

#define WAITV(n_lit) do {                                                    \
    asm volatile("s_waitcnt vmcnt(" #n_lit ")" ::: "memory");                \
    __builtin_amdgcn_sched_barrier(0);                                       \
  } while (0)
#define BARRIER() do {                                                       \
    __builtin_amdgcn_sched_barrier(0);                                       \
    __builtin_amdgcn_s_barrier();                                            \
    __builtin_amdgcn_sched_barrier(0);                                       \
  } while (0)

  STAGE(ldsA0, ldsB0, 0);                                   // 8 in flight
  STAGE(ldsA1, ldsB1, 1); WAITV(8); BARRIER();              // slab0 landed
  COMPUTE(ldsA0, ldsB0); BARRIER();
  STAGE(ldsA0, ldsB0, 2); WAITV(8); BARRIER();
  COMPUTE(ldsA1, ldsB1); BARRIER();
  STAGE(ldsA1, ldsB1, 3); WAITV(8); BARRIER();
  COMPUTE(ldsA0, ldsB0); BARRIER();
  STAGE(ldsA0, ldsB0, 4); WAITV(8); BARRIER();
  COMPUTE(ldsA1, ldsB1); BARRIER();
  STAGE(ldsA1, ldsB1, 5); WAITV(8); BARRIER();
  COMPUTE(ldsA0, ldsB0); BARRIER();
  STAGE(ldsA0, ldsB0, 6); WAITV(8); BARRIER();
  COMPUTE(ldsA1, ldsB1); BARRIER();
  STAGE(ldsA1, ldsB1, 7); WAITV(8); BARRIER();
  COMPUTE(ldsA0, ldsB0); BARRIER();
  WAITV(0); BARRIER();                                      // drain slab 7
  COMPUTE(ldsA1, ldsB1);

  // Epilogue: C/D layout col=lane&15, row=quad*4+reg (shape-determined,
  // dtype-independent, verified m89/m121 + in-session absmax=0)
  float lsum = 0.0f;
  #pragma unroll
  for (int mi = 0; mi < 8; ++mi) {
    const int gibase = by * BM + wm * 128 + mi * 16 + quad * 4;
    #pragma unroll
    for (int r = 0; r < 4; ++r) {
      const int gi = gibase + r;
      const float di = dvec[gi];  // fp32 diagonal (accurate)
      #pragma unroll
      for (int ni = 0; ni < 4; ++ni) {
        const int gj = bx * BN + wn * 64 + ni * 16 + lrow;
        const float s = (float)acc[mi][ni][r] * INVQS2;
        lsum += (gi == gj) ? (1.0f - s) : fmaxf(MARGIN - s + di, 0.0f);
      }
    }
  }
  #pragma unroll
  for (int off = 32; off; off >>= 1) lsum += __shfl_down(lsum, off, 64);
  __shared__ float bsum[8];
  if (ln == 0) bsum[wv] = lsum;
  __syncthreads();
  if (t == 0) {
    float tot = 0.f;
    #pragma unroll
    for (int i = 0; i < 8; ++i) tot += bsum[i];
    atomicAdd(out, tot * (1.0f / ((float)N * (float)N)));
  }
}

extern "C" void kernel_launch(void* const* d_in, const int* in_sizes, int n_in,
                              void* d_out, int out_size, void* d_ws, size_t ws_size,
                              hipStream_t stream) {
  const float* W = (const float*)d_in[0];  // wsi_embeddings (N,1,D)
  const float* O = (const float*)d_in[1];  // omic_embeddings (N,1,D)
  uint8_t* Wn = (uint8_t*)d_ws;                     // 4 MB i8
  uint8_t* On = Wn + (size_t)N * D;                 // 4 MB i8
  float* dvec = (float*)(On + (size_t)N * D);       // 16 KB
  float* out = (float*)d_out;

  prep_kernel<<<N / 4, 256, 0, stream>>>(W, O, Wn, On, dvec, out);
  dim3 grid(N / BN, N / BM);  // 16 x 16 = 256 blocks = 1 per CU
  gemm_loss_kernel<<<grid, 512, 0, stream>>>(Wn, On, dvec, out);
}